// Round 1
// baseline (159.987 us; speedup 1.0000x reference)
//
#include <hip/hip_runtime.h>

// SemiSparseCRFLoss on MI355X.
// Inputs: d_in[0]=y_pr f32 (16,2,512,512), d_in[1]=y_gt i32 (unused),
//         d_in[2]=image f32 (16,3,512,512), d_in[3]=image_class i32 (16,)
// Output: d_out[0] = scalar f32 loss.
//
// loss = 1/(4*B*H*W) * sum over shifts {(0,1),(1,0),(1,1),(1,-1)}, b with
//        image_class[b]!=0, valid (h,w):
//        (exp(-d2/(2*0.15^2))*exp(-(dy^2+dx^2)/2) - 0.01) * (y - y_shift)^2
// where d2 = sum_c (I_c - I_c_shift)^2 over 3 channels.

#define BATCH 16
#define HGT 512
#define WID 512
#define HW (HGT * WID)
#define NPIX (BATCH * HW)

__global__ void crf_init(double* acc) {
    if (threadIdx.x == 0 && blockIdx.x == 0) acc[0] = 0.0;
}

__global__ __launch_bounds__(256) void crf_main(
        const float* __restrict__ y_pr,
        const float* __restrict__ image,
        const int* __restrict__ image_class,
        double* __restrict__ acc) {
    const float inv2s2 = 1.0f / (2.0f * 0.15f * 0.15f);   // 22.2222
    const float wxy1 = 0.60653066f;   // exp(-1/2) for (0,1),(1,0)
    const float wxy2 = 0.36787944f;   // exp(-1)   for (1,1),(1,-1)

    double local = 0.0;
    const int stride = gridDim.x * blockDim.x;
    for (int idx = blockIdx.x * blockDim.x + threadIdx.x; idx < NPIX; idx += stride) {
        const int b = idx >> 18;              // HW = 2^18
        if (image_class[b] == 0) continue;    // sel = 0 -> skip all loads
        const int hw = idx & (HW - 1);
        const int h = hw >> 9;                // W = 2^9
        const int w = hw & (WID - 1);

        const float* __restrict__ yb = y_pr + (size_t)b * 2 * HW + HW;  // channel 1
        const float* __restrict__ ib = image + (size_t)b * 3 * HW;

        const float y0 = yb[hw];
        const float i0 = ib[hw];
        const float i1 = ib[HW + hw];
        const float i2 = ib[2 * HW + hw];

        float s = 0.0f;
        const bool hn = (h + 1 < HGT);

        // shift (0,1): neighbor (h, w+1)
        if (w + 1 < WID) {
            const int n = hw + 1;
            const float dy_ = y0 - yb[n];
            const float d0 = i0 - ib[n];
            const float d1 = i1 - ib[HW + n];
            const float d2 = i2 - ib[2 * HW + n];
            const float dsq = d0 * d0 + d1 * d1 + d2 * d2;
            const float m = expf(-dsq * inv2s2) * wxy1 - 0.01f;
            s += m * dy_ * dy_;
        }
        // shift (1,0): neighbor (h+1, w)
        if (hn) {
            const int n = hw + WID;
            const float dy_ = y0 - yb[n];
            const float d0 = i0 - ib[n];
            const float d1 = i1 - ib[HW + n];
            const float d2 = i2 - ib[2 * HW + n];
            const float dsq = d0 * d0 + d1 * d1 + d2 * d2;
            const float m = expf(-dsq * inv2s2) * wxy1 - 0.01f;
            s += m * dy_ * dy_;
        }
        // shift (1,1): neighbor (h+1, w+1)
        if (hn && (w + 1 < WID)) {
            const int n = hw + WID + 1;
            const float dy_ = y0 - yb[n];
            const float d0 = i0 - ib[n];
            const float d1 = i1 - ib[HW + n];
            const float d2 = i2 - ib[2 * HW + n];
            const float dsq = d0 * d0 + d1 * d1 + d2 * d2;
            const float m = expf(-dsq * inv2s2) * wxy2 - 0.01f;
            s += m * dy_ * dy_;
        }
        // shift (1,-1): neighbor (h+1, w-1)
        if (hn && (w - 1 >= 0)) {
            const int n = hw + WID - 1;
            const float dy_ = y0 - yb[n];
            const float d0 = i0 - ib[n];
            const float d1 = i1 - ib[HW + n];
            const float d2 = i2 - ib[2 * HW + n];
            const float dsq = d0 * d0 + d1 * d1 + d2 * d2;
            const float m = expf(-dsq * inv2s2) * wxy2 - 0.01f;
            s += m * dy_ * dy_;
        }
        local += (double)s;
    }

    // wave64 shuffle reduction (double -> two 32-bit shuffles, fine)
    for (int off = 32; off > 0; off >>= 1)
        local += __shfl_down(local, off);

    __shared__ double sdata[4];   // 256 threads = 4 waves
    const int lane = threadIdx.x & 63;
    const int wid = threadIdx.x >> 6;
    if (lane == 0) sdata[wid] = local;
    __syncthreads();
    if (threadIdx.x == 0) {
        double t = sdata[0] + sdata[1] + sdata[2] + sdata[3];
        atomicAdd(acc, t);   // device-scope f64 atomic
    }
}

__global__ void crf_final(const double* __restrict__ acc, float* __restrict__ out) {
    if (threadIdx.x == 0 && blockIdx.x == 0) {
        // scale: WEIGHT * (1/B) * (1/(H*W)) * (1/len(SHIFTS))
        out[0] = (float)(acc[0] / ((double)HW * BATCH * 4));
    }
}

extern "C" void kernel_launch(void* const* d_in, const int* in_sizes, int n_in,
                              void* d_out, int out_size, void* d_ws, size_t ws_size,
                              hipStream_t stream) {
    const float* y_pr = (const float*)d_in[0];
    // d_in[1] (y_gt) unused by the reference
    const float* image = (const float*)d_in[2];
    const int* image_class = (const int*)d_in[3];
    float* out = (float*)d_out;
    double* acc = (double*)d_ws;

    crf_init<<<1, 64, 0, stream>>>(acc);
    crf_main<<<4096, 256, 0, stream>>>(y_pr, image, image_class, acc);
    crf_final<<<1, 64, 0, stream>>>(acc, out);
}